// Round 1
// baseline (349.156 us; speedup 1.0000x reference)
//
#include <hip/hip_runtime.h>
#include <hip/hip_bf16.h>
#include <cstdint>
#include <cstddef>

// Problem constants
#define N_NODES 4096
#define F_IN    256
#define H_HEADS 4
#define D_HEAD  64
#define FEAT    256           // H*D
#define SLOPE   0.2f
#define LN_EPS  1e-5f

// Attention tiling
#define NCHUNK  4
#define J_CHUNK 1024
#define I_TILE  32
#define J_TILE  64
#define P_PAD   36            // 144 B rows: 16B-aligned for ds_read_b128, 8-way-max write conflicts

// Workspace layout (bytes). Total ~21.6 MB.
#define FLAG_OFF  0
#define WX_OFF    256
#define WX_BYTES  ((size_t)N_NODES * FEAT * 4)
#define SSRC_OFF  (WX_OFF + WX_BYTES)
#define S_BYTES   ((size_t)N_NODES * H_HEADS * 4)
#define SDST_OFF  (SSRC_OFF + S_BYTES)
#define ML_OFF    (SDST_OFF + S_BYTES)
#define ML_BYTES  ((size_t)NCHUNK * N_NODES * H_HEADS * 2 * 4)
#define ACC_OFF   (ML_OFF + ML_BYTES)

// ---------------------------------------------------------------------------
// Adjacency dtype detection: JAX bool = 1 byte, but harness may widen to i32.
// If int32 {0,1}: every byte at idx%4!=0 is zero. For real u8 bernoulli data,
// 3072 random bytes all zero has prob ~2^-3072. Flag=1 -> int32 layout.
// ---------------------------------------------------------------------------
__global__ void detect_kernel(const uint8_t* __restrict__ adj, int* __restrict__ flag) {
    int t = threadIdx.x;
    uint32_t acc = 0;
    for (int idx = t; idx < 4096; idx += 64)
        if (idx & 3) acc |= adj[idx];
    unsigned long long any = __ballot(acc != 0);
    if (t == 0) *flag = (any == 0ull) ? 1 : 0;
}

// ---------------------------------------------------------------------------
// Kernel A: Wx[n,o] = sum_f x[n,f] * W[o,f].  (4096x256) = (4096x256)(256x256)^T
// 64x64 tiles, BK=64, 256 threads, 4x4 micro-tile.
// ---------------------------------------------------------------------------
__global__ __launch_bounds__(256) void gemm_wx(const float* __restrict__ x,
                                               const float* __restrict__ W,
                                               float* __restrict__ wx) {
    __shared__ float xs[64][68];
    __shared__ float wsm[64][68];
    const int ot = blockIdx.x;     // 0..3   (output-feature tile)
    const int nt = blockIdx.y;     // 0..63  (node tile)
    const int t  = threadIdx.x;
    const int tm = t >> 4, tn = t & 15;
    float acc[4][4] = {};

    for (int k0 = 0; k0 < F_IN; k0 += 64) {
        #pragma unroll
        for (int s = 0; s < 4; ++s) {
            int idx = t + s * 256;               // 0..1023
            int r = idx >> 4, c4 = (idx & 15) << 2;
            *(float4*)&xs[r][c4]  = *(const float4*)&x[(size_t)(nt * 64 + r) * F_IN + k0 + c4];
            *(float4*)&wsm[r][c4] = *(const float4*)&W[(size_t)(ot * 64 + r) * F_IN + k0 + c4];
        }
        __syncthreads();
        #pragma unroll 4
        for (int kk = 0; kk < 64; ++kk) {
            float av[4], bv[4];
            #pragma unroll
            for (int mi = 0; mi < 4; ++mi) av[mi] = xs[tm * 4 + mi][kk];
            #pragma unroll
            for (int ni = 0; ni < 4; ++ni) bv[ni] = wsm[tn * 4 + ni][kk];
            #pragma unroll
            for (int mi = 0; mi < 4; ++mi)
                #pragma unroll
                for (int ni = 0; ni < 4; ++ni)
                    acc[mi][ni] = fmaf(av[mi], bv[ni], acc[mi][ni]);
        }
        __syncthreads();
    }
    #pragma unroll
    for (int mi = 0; mi < 4; ++mi)
        #pragma unroll
        for (int ni = 0; ni < 4; ++ni)
            wx[(size_t)(nt * 64 + tm * 4 + mi) * FEAT + ot * 64 + tn * 4 + ni] = acc[mi][ni];
}

// ---------------------------------------------------------------------------
// Kernel B: s_src[n,h] = <Wx[n,h,:], a[h,0:64]>, s_dst with a[h,64:128]
// ---------------------------------------------------------------------------
__global__ __launch_bounds__(256) void svec_kernel(const float* __restrict__ Wx,
                                                   const float* __restrict__ a,
                                                   float* __restrict__ s_src,
                                                   float* __restrict__ s_dst) {
    const int t = threadIdx.x;
    const int n = blockIdx.x * 64 + (t >> 2);
    const int h = t & 3;
    const float4* row = (const float4*)(Wx + (size_t)n * FEAT + h * 64);
    const float4* as  = (const float4*)(a + h * 128);
    const float4* ad  = (const float4*)(a + h * 128 + 64);
    float ss = 0.f, sd = 0.f;
    #pragma unroll
    for (int k = 0; k < 16; ++k) {
        float4 v = row[k], va = as[k], vb = ad[k];
        ss += v.x * va.x + v.y * va.y + v.z * va.z + v.w * va.w;
        sd += v.x * vb.x + v.y * vb.y + v.z * vb.z + v.w * vb.w;
    }
    s_src[n * 4 + h] = ss;
    s_dst[n * 4 + h] = sd;
}

// ---------------------------------------------------------------------------
// Kernel C1: per (i-tile of 32, j-chunk of 1024): chunk-local softmax stats
// (m,l) and unnormalized acc[i, h*64+d] = sum_j p * Wx[j, h*64+d].
// grid = 128 tiles x 4 chunks = 512 blocks, 256 threads, LDS ~56KB (2 blk/CU).
// ---------------------------------------------------------------------------
__global__ __launch_bounds__(256) void attn_partial(const float* __restrict__ Wx,
                                                    const float* __restrict__ s_src,
                                                    const float* __restrict__ s_dst,
                                                    const void* __restrict__ adjv,
                                                    const int* __restrict__ flag,
                                                    float* __restrict__ ws_ml,
                                                    float* __restrict__ ws_acc) {
    __shared__ float   sA[I_TILE][4];          // s_src for the i-tile
    __shared__ float   msh[I_TILE][4];         // chunk-local max per (i,h)
    __shared__ float   sJ[J_CHUNK * 4];        // s_dst for the chunk, [j*4+h]
    __shared__ float   p_lds[256][P_PAD];      // p for one j-tile: row = jj*4+h, col = i
    __shared__ uint8_t adjT[I_TILE][J_TILE];   // adjacency tile

    const int bid   = blockIdx.x;
    const int tile  = bid >> 2;
    const int chunk = bid & 3;
    const int i0    = tile * I_TILE;
    const int jc    = chunk * J_CHUNK;
    const int t     = threadIdx.x;
    const int is_i32 = *flag;
    const uint8_t* adj8 = (const uint8_t*)adjv;

    // stage s_src tile + s_dst chunk
    if (t < 128) sA[t >> 2][t & 3] = s_src[(size_t)(i0 + (t >> 2)) * 4 + (t & 3)];
    {
        const float* sdc = s_dst + (size_t)jc * 4;
        #pragma unroll
        for (int k = 0; k < 16; ++k) sJ[t + k * 256] = sdc[t + k * 256];
    }
    __syncthreads();

    // ---------------- Phase A: per (i,h) chunk-local max and exp-sum --------
    {
        const int pair = t >> 1, q = t & 1;
        const int iL = pair >> 2, hA = pair & 3;
        const float si = sA[iL][hA];
        const int jbase = q * 512;
        float mm = -INFINITY;

        if (!is_i32) {
            const uint32_t* arow = (const uint32_t*)(adj8 + (size_t)(i0 + iL) * N_NODES + jc + jbase);
            for (int b = 0; b < 128; ++b) {
                uint32_t w = arow[b];
                int j4 = jbase + (b << 2);
                float v0 = sJ[(j4 + 0) * 4 + hA], v1 = sJ[(j4 + 1) * 4 + hA];
                float v2 = sJ[(j4 + 2) * 4 + hA], v3 = sJ[(j4 + 3) * 4 + hA];
                mm = fmaxf(mm, (w & 0x000000ffu) ? v0 : -INFINITY);
                mm = fmaxf(mm, (w & 0x0000ff00u) ? v1 : -INFINITY);
                mm = fmaxf(mm, (w & 0x00ff0000u) ? v2 : -INFINITY);
                mm = fmaxf(mm, (w & 0xff000000u) ? v3 : -INFINITY);
            }
        } else {
            const int4* arow = (const int4*)((const int*)adjv + (size_t)(i0 + iL) * N_NODES + jc + jbase);
            for (int b = 0; b < 128; ++b) {
                int4 w = arow[b];
                int j4 = jbase + (b << 2);
                float v0 = sJ[(j4 + 0) * 4 + hA], v1 = sJ[(j4 + 1) * 4 + hA];
                float v2 = sJ[(j4 + 2) * 4 + hA], v3 = sJ[(j4 + 3) * 4 + hA];
                mm = fmaxf(mm, w.x ? v0 : -INFINITY);
                mm = fmaxf(mm, w.y ? v1 : -INFINITY);
                mm = fmaxf(mm, w.z ? v2 : -INFINITY);
                mm = fmaxf(mm, w.w ? v3 : -INFINITY);
            }
        }
        // lrelu monotone -> local score max
        float eM = si + mm;
        eM = fmaxf(eM, SLOPE * eM);

        float l = 0.f;
        if (!is_i32) {
            const uint32_t* arow = (const uint32_t*)(adj8 + (size_t)(i0 + iL) * N_NODES + jc + jbase);
            for (int b = 0; b < 128; ++b) {
                uint32_t w = arow[b];
                int j4 = jbase + (b << 2);
                #pragma unroll
                for (int k = 0; k < 4; ++k) {
                    float e = si + sJ[(j4 + k) * 4 + hA];
                    e = fmaxf(e, SLOPE * e);
                    float p = __expf(e - eM);
                    l += ((w >> (8 * k)) & 0xffu) ? p : 0.f;
                }
            }
        } else {
            const int4* arow = (const int4*)((const int*)adjv + (size_t)(i0 + iL) * N_NODES + jc + jbase);
            for (int b = 0; b < 128; ++b) {
                int4 w = arow[b];
                int j4 = jbase + (b << 2);
                int m4[4] = {w.x, w.y, w.z, w.w};
                #pragma unroll
                for (int k = 0; k < 4; ++k) {
                    float e = si + sJ[(j4 + k) * 4 + hA];
                    e = fmaxf(e, SLOPE * e);
                    float p = __expf(e - eM);
                    l += m4[k] ? p : 0.f;
                }
            }
        }
        // combine the two j-halves (lanes t, t^1)
        float m2 = __shfl_xor(eM, 1, 64);
        float l2 = __shfl_xor(l, 1, 64);
        float M = fmaxf(eM, m2);
        float w1 = (eM >= M) ? 1.f : __expf(eM - M);   // -inf/-inf safe
        float w2 = (m2 >= M) ? 1.f : __expf(m2 - M);
        float L = l * w1 + l2 * w2;
        msh[iL][hA] = M;
        if (q == 0) {
            size_t idx = ((size_t)chunk * N_NODES + (i0 + iL)) * H_HEADS + hA;
            ws_ml[idx * 2]     = M;
            ws_ml[idx * 2 + 1] = L;
        }
    }
    __syncthreads();

    // ---------------- Phase B: acc[i] += p * Wx[j, h*64+d] -----------------
    const int hB = t >> 6, dB = t & 63;   // wave per head
    float acc[I_TILE];
    #pragma unroll
    for (int i = 0; i < I_TILE; ++i) acc[i] = 0.f;
    const float* wxcol = Wx + hB * 64 + dB;

    for (int jt = 0; jt < J_CHUNK; jt += J_TILE) {
        // stage adjacency tile (32 x 64)
        if (!is_i32) {
            int r = t >> 3, c = t & 7;
            *(uint2*)&adjT[r][c * 8] =
                *(const uint2*)(adj8 + (size_t)(i0 + r) * N_NODES + jc + jt + c * 8);
        } else {
            #pragma unroll
            for (int k2 = 0; k2 < 2; ++k2) {
                int idx = t + k2 * 256;              // 0..511
                int r = idx >> 4, c = idx & 15;
                int4 v = *(const int4*)((const int*)adjv +
                                        (size_t)(i0 + r) * N_NODES + jc + jt + c * 4);
                adjT[r][c * 4 + 0] = v.x ? 1 : 0;
                adjT[r][c * 4 + 1] = v.y ? 1 : 0;
                adjT[r][c * 4 + 2] = v.z ? 1 : 0;
                adjT[r][c * 4 + 3] = v.w ? 1 : 0;
            }
        }
        __syncthreads();

        // B1: thread (jj,hh) computes p for all 32 i into its p_lds row
        {
            const int jj = t >> 2, hh = t & 3;
            const float sj = sJ[(jt + jj) * 4 + hh];
            float* prow = p_lds[t];                  // row index == jj*4+hh == t
            #pragma unroll 4
            for (int i = 0; i < I_TILE; ++i) {
                float e = sA[i][hh] + sj;
                e = fmaxf(e, SLOPE * e);
                float p = __expf(e - msh[i][hh]);
                prow[i] = adjT[i][jj] ? p : 0.f;
            }
        }
        __syncthreads();

        // B2: wave h, lane d: acc[i] += p[i,j,h] * Wx[j, h*64+d]
        {
            const float* base = wxcol + (size_t)(jc + jt) * FEAT;
            #pragma unroll 4
            for (int j = 0; j < J_TILE; ++j) {
                float v = base[(size_t)j * FEAT];
                const float4* pr = (const float4*)&p_lds[(j << 2) + hB][0];
                #pragma unroll
                for (int ii = 0; ii < 8; ++ii) {
                    float4 p4 = pr[ii];
                    acc[ii * 4 + 0] = fmaf(p4.x, v, acc[ii * 4 + 0]);
                    acc[ii * 4 + 1] = fmaf(p4.y, v, acc[ii * 4 + 1]);
                    acc[ii * 4 + 2] = fmaf(p4.z, v, acc[ii * 4 + 2]);
                    acc[ii * 4 + 3] = fmaf(p4.w, v, acc[ii * 4 + 3]);
                }
            }
        }
        __syncthreads();
    }

    #pragma unroll
    for (int i = 0; i < I_TILE; ++i)
        ws_acc[((size_t)chunk * N_NODES + i0 + i) * FEAT + t] = acc[i];
}

// ---------------------------------------------------------------------------
// Kernel C2: combine 4 chunk partials, normalize, residual, LayerNorm.
// grid = 4096 (one row each), 256 threads (one feature each).
// ---------------------------------------------------------------------------
__global__ __launch_bounds__(256) void finalize_kernel(const float* __restrict__ x,
                                                       const float* __restrict__ gamma,
                                                       const float* __restrict__ beta,
                                                       const float* __restrict__ ws_ml,
                                                       const float* __restrict__ ws_acc,
                                                       float* __restrict__ out) {
    const int i = blockIdx.x;
    const int t = threadIdx.x;
    const int h = t >> 6;
    const int lane = t & 63;

    float mc[NCHUNK], lc[NCHUNK];
    float M = -INFINITY;
    #pragma unroll
    for (int c = 0; c < NCHUNK; ++c) {
        size_t idx = ((size_t)c * N_NODES + i) * H_HEADS + h;
        mc[c] = ws_ml[idx * 2];
        lc[c] = ws_ml[idx * 2 + 1];
        M = fmaxf(M, mc[c]);
    }
    float L = 0.f, y = 0.f;
    #pragma unroll
    for (int c = 0; c < NCHUNK; ++c) {
        float wt = (mc[c] >= M) ? 1.f : __expf(mc[c] - M);
        L += lc[c] * wt;
        y += ws_acc[((size_t)c * N_NODES + i) * FEAT + t] * wt;
    }
    float inv = (L > 0.f) ? (1.f / L) : 0.f;
    y = y * inv + x[(size_t)i * FEAT + t];

    // LayerNorm over the 256 features (block-wide reduction)
    float s1 = y, s2 = y * y;
    #pragma unroll
    for (int o = 32; o > 0; o >>= 1) {
        s1 += __shfl_xor(s1, o, 64);
        s2 += __shfl_xor(s2, o, 64);
    }
    __shared__ float red1[4], red2[4];
    if (lane == 0) { red1[h] = s1; red2[h] = s2; }
    __syncthreads();
    s1 = red1[0] + red1[1] + red1[2] + red1[3];
    s2 = red2[0] + red2[1] + red2[2] + red2[3];
    float mu  = s1 * (1.f / 256.f);
    float var = s2 * (1.f / 256.f) - mu * mu;
    float r = 1.0f / sqrtf(var + LN_EPS);
    out[(size_t)i * FEAT + t] = (y - mu) * r * gamma[t] + beta[t];
}

// ---------------------------------------------------------------------------
extern "C" void kernel_launch(void* const* d_in, const int* in_sizes, int n_in,
                              void* d_out, int out_size, void* d_ws, size_t ws_size,
                              hipStream_t stream) {
    const float* x     = (const float*)d_in[0];
    const void*  adj   = d_in[1];
    const float* W     = (const float*)d_in[2];
    const float* a     = (const float*)d_in[3];
    const float* gamma = (const float*)d_in[4];
    const float* beta  = (const float*)d_in[5];
    float* out = (float*)d_out;

    char* ws = (char*)d_ws;
    int*   flag   = (int*)(ws + FLAG_OFF);
    float* Wx     = (float*)(ws + WX_OFF);
    float* s_src  = (float*)(ws + SSRC_OFF);
    float* s_dst  = (float*)(ws + SDST_OFF);
    float* ws_ml  = (float*)(ws + ML_OFF);
    float* ws_acc = (float*)(ws + ACC_OFF);

    detect_kernel<<<1, 64, 0, stream>>>((const uint8_t*)adj, flag);
    gemm_wx<<<dim3(4, 64), 256, 0, stream>>>(x, W, Wx);
    svec_kernel<<<64, 256, 0, stream>>>(Wx, a, s_src, s_dst);
    attn_partial<<<512, 256, 0, stream>>>(Wx, s_src, s_dst, adj, flag, ws_ml, ws_acc);
    finalize_kernel<<<N_NODES, 256, 0, stream>>>(x, gamma, beta, ws_ml, ws_acc, out);
}

// Round 2
// 183.710 us; speedup vs baseline: 1.9006x; 1.9006x over previous
//
#include <hip/hip_runtime.h>
#include <hip/hip_bf16.h>
#include <cstdint>
#include <cstddef>

// Problem constants
#define N_NODES 4096
#define F_IN    256
#define H_HEADS 4
#define D_HEAD  64
#define FEAT    256           // H*D
#define SLOPE   0.2f
#define LN_EPS  1e-5f

// Attention tiling
#define NCHUNK  4
#define J_CHUNK 1024
#define I_TILE  32
#define K_STEP  32
#define NSTEP   (J_CHUNK / K_STEP)   // 32

typedef __attribute__((ext_vector_type(8))) short bf16x8;
typedef __attribute__((ext_vector_type(4))) float f32x4;

// Workspace layout (bytes). Total ~20.5 MB (previous round used 21.6 MB OK).
#define FLAG_OFF   0
#define GMAX_OFF   64
#define ADJB_OFF   256
#define ADJB_BYTES ((size_t)N_NODES * 128 * 4)                 // 2 MB bitmask
#define WXT_OFF    (ADJB_OFF + ADJB_BYTES)
#define WXT_BYTES  ((size_t)FEAT * N_NODES * 2)                // 2 MB bf16, [feat][node]
#define SSRC_OFF   (WXT_OFF + WXT_BYTES)
#define SVEC_BYTES ((size_t)H_HEADS * N_NODES * 4)             // 64 KB planar
#define SDST_OFF   (SSRC_OFF + SVEC_BYTES)
#define WSL_OFF    (SDST_OFF + SVEC_BYTES)
#define WSL_BYTES  ((size_t)NCHUNK * N_NODES * H_HEADS * 4)    // 256 KB
#define WSACC_OFF  (WSL_OFF + WSL_BYTES)
#define WSACC_BYTES ((size_t)NCHUNK * N_NODES * FEAT * 4)      // 16 MB

// ---------------------------------------------------------------------------
// helpers
// ---------------------------------------------------------------------------
__device__ __forceinline__ short f2bf(float f) {   // RNE f32 -> bf16 bits
    uint32_t u = __float_as_uint(f);
    uint32_t r = (u + 0x7fffu + ((u >> 16) & 1u)) >> 16;
    return (short)r;
}
__device__ __forceinline__ uint32_t fkey(float f) {    // order-preserving f32->u32
    uint32_t u = __float_as_uint(f);
    return ((int)u < 0) ? ~u : (u | 0x80000000u);
}
__device__ __forceinline__ float funkey(uint32_t k) {
    uint32_t u = (k & 0x80000000u) ? (k & 0x7fffffffu) : ~k;
    return __uint_as_float(u);
}

// ---------------------------------------------------------------------------
// Adjacency dtype detection (u8 bool vs widened int32) + gmax init.
// ---------------------------------------------------------------------------
__global__ void detect_kernel(const uint8_t* __restrict__ adj,
                              int* __restrict__ flag, uint32_t* __restrict__ gmax) {
    int t = threadIdx.x;
    uint32_t acc = 0;
    for (int idx = t; idx < 4096; idx += 64)
        if (idx & 3) acc |= adj[idx];
    unsigned long long any = __ballot(acc != 0);
    if (t == 0) *flag = (any == 0ull) ? 1 : 0;
    if (t < H_HEADS) gmax[t] = 0u;   // key-space floor
}

// ---------------------------------------------------------------------------
// Bit-pack adjacency: bits[row][w] bit b = (adj[row][w*32+b] != 0).
// grid 2048 x 256: one u32 word per thread.
// ---------------------------------------------------------------------------
__global__ __launch_bounds__(256) void pack_adj(const uint8_t* __restrict__ adj8,
                                                const int* __restrict__ flag,
                                                uint32_t* __restrict__ bits) {
    int gid = blockIdx.x * 256 + threadIdx.x;      // 0..524287
    uint32_t b = 0;
    if (!(*flag)) {
        const uint32_t* src = (const uint32_t*)adj8 + (size_t)gid * 8;  // 32 bytes
        #pragma unroll
        for (int k = 0; k < 8; ++k) {
            uint32_t v = src[k];
            if (v & 0x000000ffu) b |= 1u << (k * 4 + 0);
            if (v & 0x0000ff00u) b |= 1u << (k * 4 + 1);
            if (v & 0x00ff0000u) b |= 1u << (k * 4 + 2);
            if (v & 0xff000000u) b |= 1u << (k * 4 + 3);
        }
    } else {
        const int4* src = (const int4*)adj8 + (size_t)gid * 8;          // 32 ints
        #pragma unroll
        for (int k = 0; k < 8; ++k) {
            int4 v = src[k];
            if (v.x) b |= 1u << (k * 4 + 0);
            if (v.y) b |= 1u << (k * 4 + 1);
            if (v.z) b |= 1u << (k * 4 + 2);
            if (v.w) b |= 1u << (k * 4 + 3);
        }
    }
    bits[gid] = b;
}

// ---------------------------------------------------------------------------
// GEMM Wx = x @ W^T fused with: WxT bf16 transpose-out, s_src/s_dst planar,
// per-head global max of s_dst (atomic, order-independent).
// grid (4 heads, 64 node-tiles) x 256 threads.
// ---------------------------------------------------------------------------
__global__ __launch_bounds__(256) void gemm_wx(const float* __restrict__ x,
                                               const float* __restrict__ W,
                                               const float* __restrict__ a,
                                               short* __restrict__ WxT,
                                               float* __restrict__ s_srcT,
                                               float* __restrict__ s_dstT,
                                               uint32_t* __restrict__ gmax) {
    __shared__ float xs[64][68];
    __shared__ float wsm[64][68];
    __shared__ float aS[64], aD[64];
    __shared__ float wredmax[4];
    const int h  = blockIdx.x;     // head = 64-feature group
    const int nt = blockIdx.y;     // node tile
    const int t  = threadIdx.x;
    const int tm = t >> 4, tn = t & 15;
    if (t < 64)       aS[t]      = a[h * 128 + t];
    else if (t < 128) aD[t - 64] = a[h * 128 + 64 + (t - 64)];
    float acc[4][4] = {};

    for (int k0 = 0; k0 < F_IN; k0 += 64) {
        #pragma unroll
        for (int s = 0; s < 4; ++s) {
            int idx = t + s * 256;
            int r = idx >> 4, c4 = (idx & 15) << 2;
            *(float4*)&xs[r][c4]  = *(const float4*)&x[(size_t)(nt * 64 + r) * F_IN + k0 + c4];
            *(float4*)&wsm[r][c4] = *(const float4*)&W[(size_t)(h * 64 + r) * F_IN + k0 + c4];
        }
        __syncthreads();
        #pragma unroll 4
        for (int kk = 0; kk < 64; ++kk) {
            float av[4], bv[4];
            #pragma unroll
            for (int mi = 0; mi < 4; ++mi) av[mi] = xs[tm * 4 + mi][kk];
            #pragma unroll
            for (int ni = 0; ni < 4; ++ni) bv[ni] = wsm[tn * 4 + ni][kk];
            #pragma unroll
            for (int mi = 0; mi < 4; ++mi)
                #pragma unroll
                for (int ni = 0; ni < 4; ++ni)
                    acc[mi][ni] = fmaf(av[mi], bv[ni], acc[mi][ni]);
        }
        __syncthreads();
    }

    // WxT bf16 transposed write: [feat][node], 8B runs over consecutive nodes
    #pragma unroll
    for (int ni = 0; ni < 4; ++ni) {
        short4 sv;
        sv.x = f2bf(acc[0][ni]); sv.y = f2bf(acc[1][ni]);
        sv.z = f2bf(acc[2][ni]); sv.w = f2bf(acc[3][ni]);
        *(short4*)&WxT[(size_t)(h * 64 + tn * 4 + ni) * N_NODES + nt * 64 + tm * 4] = sv;
    }

    // s_src / s_dst: partial over this thread's 4 features, reduce over tn
    float ps[4] = {0.f, 0.f, 0.f, 0.f}, pd[4] = {0.f, 0.f, 0.f, 0.f};
    #pragma unroll
    for (int mi = 0; mi < 4; ++mi)
        #pragma unroll
        for (int ni = 0; ni < 4; ++ni) {
            float v = acc[mi][ni];
            ps[mi] = fmaf(v, aS[tn * 4 + ni], ps[mi]);
            pd[mi] = fmaf(v, aD[tn * 4 + ni], pd[mi]);
        }
    #pragma unroll
    for (int o = 1; o < 16; o <<= 1) {
        #pragma unroll
        for (int mi = 0; mi < 4; ++mi) {
            ps[mi] += __shfl_xor(ps[mi], o, 64);
            pd[mi] += __shfl_xor(pd[mi], o, 64);
        }
    }
    float lmax = -INFINITY;
    if (tn == 0) {
        #pragma unroll
        for (int mi = 0; mi < 4; ++mi) {
            int node = nt * 64 + tm * 4 + mi;
            s_srcT[(size_t)h * N_NODES + node] = ps[mi];
            s_dstT[(size_t)h * N_NODES + node] = pd[mi];
            lmax = fmaxf(lmax, pd[mi]);
        }
    }
    #pragma unroll
    for (int o = 1; o < 64; o <<= 1) lmax = fmaxf(lmax, __shfl_xor(lmax, o, 64));
    if ((t & 63) == 0) wredmax[t >> 6] = lmax;
    __syncthreads();
    if (t == 0) {
        float m = fmaxf(fmaxf(wredmax[0], wredmax[1]), fmaxf(wredmax[2], wredmax[3]));
        atomicMax(&gmax[h], fkey(m));
    }
}

// ---------------------------------------------------------------------------
// Attention chunk kernel: 512 blocks (128 i-tiles x 4 j-chunks) x 512 threads.
// Wave = (head, i-half). P generated per-lane directly in MFMA A-layout
// (row=lane&15, k=(lane>>4)*8+e); B = WxT tile (LDS, double-buffered, padded);
// ones-column B-fragment accumulates softmax denominator l.
// Stabilizer: m_i = lrelu(s_i + gmax_h)  (global unmasked max — valid & safe).
// ---------------------------------------------------------------------------
__global__ __launch_bounds__(512, 4) void attn_chunk(const short* __restrict__ WxT,
                                                     const float* __restrict__ s_srcT,
                                                     const float* __restrict__ s_dstT,
                                                     const uint32_t* __restrict__ adjbits,
                                                     const uint32_t* __restrict__ gmax,
                                                     float* __restrict__ ws_l,
                                                     float* __restrict__ ws_acc) {
    __shared__ short    Bt[2][256][40];     // K_STEP=32 elems + pad to 40 (80B rows)
    __shared__ uint32_t adjW[32][33];       // chunk bitmask, +1 word pad
    __shared__ float    sJ[4][1032];        // s_dst slice per head, +8 pad

    const int t     = threadIdx.x;
    const int tile  = blockIdx.x >> 2;
    const int chunk = blockIdx.x & 3;
    const int i0    = tile * I_TILE;
    const int jc    = chunk * J_CHUNK;
    const int wave  = t >> 6, lane = t & 63;
    const int h     = wave & 3, mh = wave >> 2;
    const int col   = lane & 15, q = lane >> 4;

    // ---- stage adjacency bits, sJ, and Bt[0] ----
    for (int s2 = t; s2 < 1024; s2 += 512)
        adjW[s2 >> 5][s2 & 31] =
            adjbits[(size_t)(i0 + (s2 >> 5)) * 128 + chunk * 32 + (s2 & 31)];
    for (int s2 = t; s2 < 1024; s2 += 512) {
        int pl = s2 >> 8, off = (s2 & 255) * 4;
        *(float4*)&sJ[pl][off] = *(const float4*)&s_dstT[(size_t)pl * N_NODES + jc + off];
    }
    const int sf = t >> 1, shalf = t & 1;
    const int4* gsrc = (const int4*)(WxT + (size_t)sf * N_NODES + jc);
    {
        int4 v0 = gsrc[shalf * 2 + 0], v1 = gsrc[shalf * 2 + 1];
        int4* ld = (int4*)&Bt[0][sf][shalf * 16];
        ld[0] = v0; ld[1] = v1;
    }
    __syncthreads();

    const int   iL  = mh * 16 + col;             // local row (A-frag row = lane&15)
    const int   i   = i0 + iL;
    const float si  = s_srcT[(size_t)h * N_NODES + i];
    const float gm  = funkey(gmax[h]);
    const float em0 = si + gm;
    const float mi_ = fmaxf(em0, SLOPE * em0);   // lrelu(si + gmax)

    f32x4 cacc[4], cl;
    #pragma unroll
    for (int n = 0; n < 4; ++n)
        #pragma unroll
        for (int r2 = 0; r2 < 4; ++r2) cacc[n][r2] = 0.f;
    #pragma unroll
    for (int r2 = 0; r2 < 4; ++r2) cl[r2] = 0.f;

    bf16x8 onesf;
    #pragma unroll
    for (int e = 0; e < 8; ++e) onesf[e] = (col == 0) ? (short)0x3F80 : (short)0;

    for (int ks = 0; ks < NSTEP; ++ks) {
        const int  cur  = ks & 1;
        const bool more = (ks + 1 < NSTEP);
        int4 pf0, pf1;
        if (more) {
            pf0 = gsrc[(ks + 1) * 4 + shalf * 2 + 0];
            pf1 = gsrc[(ks + 1) * 4 + shalf * 2 + 1];
        }

        // ---- A fragment: p for 8 j's (j = ks*32 + q*8 + jj) ----
        uint32_t wq = adjW[iL][ks] >> (q * 8);
        const float4 sa = *(const float4*)&sJ[h][ks * 32 + q * 8];
        const float4 sb = *(const float4*)&sJ[h][ks * 32 + q * 8 + 4];
        float sjv[8] = {sa.x, sa.y, sa.z, sa.w, sb.x, sb.y, sb.z, sb.w};
        bf16x8 ap;
        #pragma unroll
        for (int jj = 0; jj < 8; ++jj) {
            float e = si + sjv[jj];
            e = fmaxf(e, SLOPE * e);
            float p = __expf(e - mi_);
            p = (wq & (1u << jj)) ? p : 0.f;
            ap[jj] = f2bf(p);
        }

        // ---- MFMA against 4 d-tiles + ones column ----
        #pragma unroll
        for (int n = 0; n < 4; ++n) {
            bf16x8 bfr = *(const bf16x8*)&Bt[cur][h * 64 + n * 16 + col][q * 8];
            cacc[n] = __builtin_amdgcn_mfma_f32_16x16x32_bf16(ap, bfr, cacc[n], 0, 0, 0);
        }
        cl = __builtin_amdgcn_mfma_f32_16x16x32_bf16(ap, onesf, cl, 0, 0, 0);

        // ---- write next B tile (loads issued before compute) ----
        if (more) {
            int4* ld = (int4*)&Bt[cur ^ 1][sf][shalf * 16];
            ld[0] = pf0; ld[1] = pf1;
        }
        __syncthreads();
    }

    // ---- epilogue: C layout col=lane&15, row=(lane>>4)*4+reg ----
    #pragma unroll
    for (int n = 0; n < 4; ++n)
        #pragma unroll
        for (int r = 0; r < 4; ++r) {
            int ii = i0 + mh * 16 + q * 4 + r;
            ws_acc[((size_t)chunk * N_NODES + ii) * FEAT + h * 64 + n * 16 + col] = cacc[n][r];
        }
    if (col == 0) {
        #pragma unroll
        for (int r = 0; r < 4; ++r) {
            int ii = i0 + mh * 16 + q * 4 + r;
            ws_l[((size_t)chunk * N_NODES + ii) * H_HEADS + h] = cl[r];
        }
    }
}

// ---------------------------------------------------------------------------
// Finalize: sum chunk partials (shared stabilizer -> plain sums), normalize,
// residual, LayerNorm. grid 4096 x 256.
// ---------------------------------------------------------------------------
__global__ __launch_bounds__(256) void finalize_kernel(const float* __restrict__ x,
                                                       const float* __restrict__ gamma,
                                                       const float* __restrict__ beta,
                                                       const float* __restrict__ ws_l,
                                                       const float* __restrict__ ws_acc,
                                                       float* __restrict__ out) {
    const int i = blockIdx.x;
    const int t = threadIdx.x;
    const int h = t >> 6;
    const int lane = t & 63;

    float L = 0.f, y = 0.f;
    #pragma unroll
    for (int c = 0; c < NCHUNK; ++c) {
        L += ws_l[((size_t)c * N_NODES + i) * H_HEADS + h];
        y += ws_acc[((size_t)c * N_NODES + i) * FEAT + t];
    }
    y = (L > 0.f ? y / L : 0.f) + x[(size_t)i * FEAT + t];

    float s1 = y, s2 = y * y;
    #pragma unroll
    for (int o = 32; o > 0; o >>= 1) {
        s1 += __shfl_xor(s1, o, 64);
        s2 += __shfl_xor(s2, o, 64);
    }
    __shared__ float red1[4], red2[4];
    if (lane == 0) { red1[h] = s1; red2[h] = s2; }
    __syncthreads();
    s1 = red1[0] + red1[1] + red1[2] + red1[3];
    s2 = red2[0] + red2[1] + red2[2] + red2[3];
    float mu  = s1 * (1.f / 256.f);
    float var = s2 * (1.f / 256.f) - mu * mu;
    float r = 1.0f / sqrtf(var + LN_EPS);
    out[(size_t)i * FEAT + t] = (y - mu) * r * gamma[t] + beta[t];
}

// ---------------------------------------------------------------------------
extern "C" void kernel_launch(void* const* d_in, const int* in_sizes, int n_in,
                              void* d_out, int out_size, void* d_ws, size_t ws_size,
                              hipStream_t stream) {
    const float* x     = (const float*)d_in[0];
    const void*  adj   = d_in[1];
    const float* W     = (const float*)d_in[2];
    const float* a     = (const float*)d_in[3];
    const float* gamma = (const float*)d_in[4];
    const float* beta  = (const float*)d_in[5];
    float* out = (float*)d_out;

    char* ws = (char*)d_ws;
    int*      flag    = (int*)(ws + FLAG_OFF);
    uint32_t* gmax    = (uint32_t*)(ws + GMAX_OFF);
    uint32_t* adjbits = (uint32_t*)(ws + ADJB_OFF);
    short*    WxT     = (short*)(ws + WXT_OFF);
    float*    s_srcT  = (float*)(ws + SSRC_OFF);
    float*    s_dstT  = (float*)(ws + SDST_OFF);
    float*    ws_l    = (float*)(ws + WSL_OFF);
    float*    ws_acc  = (float*)(ws + WSACC_OFF);

    detect_kernel<<<1, 64, 0, stream>>>((const uint8_t*)adj, flag, gmax);
    pack_adj<<<2048, 256, 0, stream>>>((const uint8_t*)adj, flag, adjbits);
    gemm_wx<<<dim3(4, 64), 256, 0, stream>>>(x, W, a, WxT, s_srcT, s_dstT, gmax);
    attn_chunk<<<512, 512, 0, stream>>>(WxT, s_srcT, s_dstT, adjbits, gmax, ws_l, ws_acc);
    finalize_kernel<<<N_NODES, 256, 0, stream>>>(x, gamma, beta, ws_l, ws_acc, out);
}

// Round 6
// 159.833 us; speedup vs baseline: 2.1845x; 1.1494x over previous
//
#include <hip/hip_runtime.h>
#include <hip/hip_bf16.h>
#include <cstdint>
#include <cstddef>

// Problem constants
#define N_NODES 4096
#define F_IN    256
#define H_HEADS 4
#define D_HEAD  64
#define FEAT    256           // H*D
#define SLOPE   0.2f
#define LN_EPS  1e-5f

// Attention tiling
#define NCHUNK  4
#define J_CHUNK 1024
#define I_TILE  32
#define K_STEP  32
#define NSTEP   (J_CHUNK / K_STEP)   // 32

typedef __attribute__((ext_vector_type(8))) short bf16x8;
typedef __attribute__((ext_vector_type(4))) float f32x4;

// Workspace layout (bytes).
#define GMAX_OFF   64
#define ADJB_OFF   256
#define ADJB_BYTES ((size_t)N_NODES * 128 * 4)                 // 2 MB bitmask
#define WXT_OFF    (ADJB_OFF + ADJB_BYTES)
#define WXT_BYTES  ((size_t)FEAT * N_NODES * 2)                // 2 MB bf16, [feat][node]
#define SSRC_OFF   (WXT_OFF + WXT_BYTES)
#define SVEC_BYTES ((size_t)H_HEADS * N_NODES * 4)             // 64 KB planar
#define ETAB_OFF   (SSRC_OFF + SVEC_BYTES)
#define ETAB_BYTES ((size_t)H_HEADS * N_NODES * 8)             // 128 KB float2 {e^s, e^0.2s}
#define WSL_OFF    (ETAB_OFF + ETAB_BYTES)
#define WSL_BYTES  ((size_t)NCHUNK * N_NODES * H_HEADS * 4)    // 256 KB
#define WSACC_OFF  (WSL_OFF + WSL_BYTES)

// ---------------------------------------------------------------------------
// helpers
// ---------------------------------------------------------------------------
__device__ __forceinline__ short f2bf(float f) {   // RNE f32 -> bf16 bits
    uint32_t u = __float_as_uint(f);
    uint32_t r = (u + 0x7fffu + ((u >> 16) & 1u)) >> 16;
    return (short)r;
}
__device__ __forceinline__ uint32_t fkey(float f) {    // order-preserving f32->u32
    uint32_t u = __float_as_uint(f);
    return ((int)u < 0) ? ~u : (u | 0x80000000u);
}
__device__ __forceinline__ float funkey(uint32_t k) {
    uint32_t u = (k & 0x80000000u) ? (k & 0x7fffffffu) : ~k;
    return __uint_as_float(u);
}

// ---------------------------------------------------------------------------
// pack_adj (+ per-block dtype detect + gmax init).
// Each block covers 256 u32 bit-words = 8192 output bits. Detection: in the
// u8 interpretation window (8 KB), bytes at idx%4!=0 are ALL zero iff the
// buffer is int32 {0,1} (error prob 2^-6144 for bernoulli u8 data).
// ---------------------------------------------------------------------------
__global__ __launch_bounds__(256) void pack_adj(const void* __restrict__ adjv,
                                                uint32_t* __restrict__ bits,
                                                uint32_t* __restrict__ gmax) {
    __shared__ int s_u8;
    const int t   = threadIdx.x;
    const int gid = blockIdx.x * 256 + t;      // word index 0..524287
    if (blockIdx.x == 0 && t < H_HEADS) gmax[t] = 0u;   // key-space floor

    // load 8 words (32 B) in the u8 interpretation
    uint32_t w8[8];
    const uint32_t* src8 = (const uint32_t*)adjv + (size_t)gid * 8;
    #pragma unroll
    for (int k = 0; k < 8; ++k) w8[k] = src8[k];

    uint32_t off = 0;
    #pragma unroll
    for (int k = 0; k < 8; ++k) off |= (w8[k] & 0xFFFFFF00u);
    if (t == 0) s_u8 = 0;
    __syncthreads();
    if (off) s_u8 = 1;        // benign same-value race
    __syncthreads();

    uint32_t b = 0;
    if (s_u8) {
        #pragma unroll
        for (int k = 0; k < 8; ++k) {
            uint32_t v = w8[k];
            if (v & 0x000000ffu) b |= 1u << (k * 4 + 0);
            if (v & 0x0000ff00u) b |= 1u << (k * 4 + 1);
            if (v & 0x00ff0000u) b |= 1u << (k * 4 + 2);
            if (v & 0xff000000u) b |= 1u << (k * 4 + 3);
        }
    } else {
        const int4* src = (const int4*)adjv + (size_t)gid * 8;   // 32 ints
        #pragma unroll
        for (int k = 0; k < 8; ++k) {
            int4 v = src[k];
            if (v.x) b |= 1u << (k * 4 + 0);
            if (v.y) b |= 1u << (k * 4 + 1);
            if (v.z) b |= 1u << (k * 4 + 2);
            if (v.w) b |= 1u << (k * 4 + 3);
        }
    }
    bits[gid] = b;
}

// ---------------------------------------------------------------------------
// GEMM Wx = x @ W^T fused with: WxT bf16 transpose-out, s_src planar,
// ETAB = {e^{s_dst}, e^{0.2 s_dst}}, per-head global max of s_dst (atomic).
// grid (4 heads, 64 node-tiles) x 256 threads.
// Thread (tm,tn) owns nodes tm*4+mi, features tn+16*ni  (bank-conflict-free
// float4 LDS reads: row stride tn -> banks 4*tn mod 32, 2-way max).
// ---------------------------------------------------------------------------
__global__ __launch_bounds__(256) void gemm_wx(const float* __restrict__ x,
                                               const float* __restrict__ W,
                                               const float* __restrict__ a,
                                               short* __restrict__ WxT,
                                               float* __restrict__ s_srcT,
                                               float2* __restrict__ etab,
                                               uint32_t* __restrict__ gmax) {
    __shared__ float xs[64][68];
    __shared__ float wsm[64][68];
    __shared__ float aS[64], aD[64];
    __shared__ float wredmax[4];
    const int h  = blockIdx.x;     // head = 64-feature group
    const int nt = blockIdx.y;     // node tile
    const int t  = threadIdx.x;
    const int tm = t >> 4, tn = t & 15;
    if (t < 64)       aS[t]      = a[h * 128 + t];
    else if (t < 128) aD[t - 64] = a[h * 128 + 64 + (t - 64)];
    float acc[4][4] = {};

    for (int k0 = 0; k0 < F_IN; k0 += 64) {
        #pragma unroll
        for (int s = 0; s < 4; ++s) {
            int idx = t + s * 256;
            int r = idx >> 4, c4 = (idx & 15) << 2;
            *(float4*)&xs[r][c4]  = *(const float4*)&x[(size_t)(nt * 64 + r) * F_IN + k0 + c4];
            *(float4*)&wsm[r][c4] = *(const float4*)&W[(size_t)(h * 64 + r) * F_IN + k0 + c4];
        }
        __syncthreads();
        #pragma unroll 4
        for (int kq = 0; kq < 16; ++kq) {
            float4 xa[4], wb[4];
            #pragma unroll
            for (int mi = 0; mi < 4; ++mi) xa[mi] = *(const float4*)&xs[tm * 4 + mi][kq * 4];
            #pragma unroll
            for (int ni = 0; ni < 4; ++ni) wb[ni] = *(const float4*)&wsm[tn + 16 * ni][kq * 4];
            #pragma unroll
            for (int mi = 0; mi < 4; ++mi)
                #pragma unroll
                for (int ni = 0; ni < 4; ++ni) {
                    acc[mi][ni] = fmaf(xa[mi].x, wb[ni].x, acc[mi][ni]);
                    acc[mi][ni] = fmaf(xa[mi].y, wb[ni].y, acc[mi][ni]);
                    acc[mi][ni] = fmaf(xa[mi].z, wb[ni].z, acc[mi][ni]);
                    acc[mi][ni] = fmaf(xa[mi].w, wb[ni].w, acc[mi][ni]);
                }
        }
        __syncthreads();
    }

    // WxT bf16 transposed write: [feat][node]; this thread's feature o = tn+16ni
    #pragma unroll
    for (int ni = 0; ni < 4; ++ni) {
        short4 sv;
        sv.x = f2bf(acc[0][ni]); sv.y = f2bf(acc[1][ni]);
        sv.z = f2bf(acc[2][ni]); sv.w = f2bf(acc[3][ni]);
        *(short4*)&WxT[(size_t)(h * 64 + tn + 16 * ni) * N_NODES + nt * 64 + tm * 4] = sv;
    }

    // s_src / s_dst partials over this thread's 4 features, reduce over tn
    float ps[4] = {0.f, 0.f, 0.f, 0.f}, pd[4] = {0.f, 0.f, 0.f, 0.f};
    #pragma unroll
    for (int mi = 0; mi < 4; ++mi)
        #pragma unroll
        for (int ni = 0; ni < 4; ++ni) {
            float v = acc[mi][ni];
            ps[mi] = fmaf(v, aS[tn + 16 * ni], ps[mi]);
            pd[mi] = fmaf(v, aD[tn + 16 * ni], pd[mi]);
        }
    #pragma unroll
    for (int o = 1; o < 16; o <<= 1) {
        #pragma unroll
        for (int mi = 0; mi < 4; ++mi) {
            ps[mi] += __shfl_xor(ps[mi], o, 64);
            pd[mi] += __shfl_xor(pd[mi], o, 64);
        }
    }
    float lmax = -INFINITY;
    if (tn == 0) {
        #pragma unroll
        for (int mi = 0; mi < 4; ++mi) {
            int node = nt * 64 + tm * 4 + mi;
            s_srcT[(size_t)h * N_NODES + node] = ps[mi];
            etab[(size_t)h * N_NODES + node] = make_float2(__expf(pd[mi]), __expf(0.2f * pd[mi]));
            lmax = fmaxf(lmax, pd[mi]);
        }
    }
    #pragma unroll
    for (int o = 1; o < 64; o <<= 1) lmax = fmaxf(lmax, __shfl_xor(lmax, o, 64));
    if ((t & 63) == 0) wredmax[t >> 6] = lmax;
    __syncthreads();
    if (t == 0) {
        float m = fmaxf(fmaxf(wredmax[0], wredmax[1]), fmaxf(wredmax[2], wredmax[3]));
        atomicMax(&gmax[h], fkey(m));
    }
}

// ---------------------------------------------------------------------------
// Attention chunk kernel: 512 blocks (128 i-tiles x 4 j-chunks) x 512 threads.
// Exp-free P: p = (Bj >= Ti) ? Ai*Bj : A2i*B2j with {Bj,B2j} from ETAB and
// per-lane Ai=e^{si-mi}, A2i=e^{0.2si-mi}, Ti=e^{-si}; mi=lrelu(si+gmax_h).
// Truncating bf16 pack via v_perm (denominator uses same bf16 P -> ratio
// quantization cancels). 2-step-ahead register prefetch, 1 barrier/step.
// ---------------------------------------------------------------------------
__global__ __launch_bounds__(512, 4) void attn_chunk(const short* __restrict__ WxT,
                                                     const float* __restrict__ s_srcT,
                                                     const float2* __restrict__ etab,
                                                     const uint32_t* __restrict__ adjbits,
                                                     const uint32_t* __restrict__ gmax,
                                                     float* __restrict__ ws_l,
                                                     float* __restrict__ ws_acc) {
    __shared__ short    Bt[2][256][40];     // K_STEP=32 elems + pad to 40 (80B rows)
    __shared__ uint32_t adjW[32][33];       // chunk bitmask, +1 word pad
    __shared__ float    EJ[4 * 2048];       // {e^s, e^.2s} pairs per head, 32 KB

    const int t     = threadIdx.x;
    const int tile  = blockIdx.x >> 2;
    const int chunk = blockIdx.x & 3;
    const int i0    = tile * I_TILE;
    const int jc    = chunk * J_CHUNK;
    const int wave  = t >> 6, lane = t & 63;
    const int h     = wave & 3, mh = wave >> 2;
    const int col   = lane & 15, q = lane >> 4;

    // ---- stage adjacency bits + ETAB slice ----
    for (int s2 = t; s2 < 1024; s2 += 512)
        adjW[s2 >> 5][s2 & 31] =
            adjbits[(size_t)(i0 + (s2 >> 5)) * 128 + chunk * 32 + (s2 & 31)];
    {
        const float4* esrc = (const float4*)etab;   // [h][4096] float2 = [h][2048] float4
        for (int s2 = t; s2 < 2048; s2 += 512) {
            int pl = s2 >> 9, off = s2 & 511;
            *(float4*)&EJ[pl * 2048 + off * 4] = esrc[(size_t)pl * 2048 + (jc >> 1) + off];
        }
    }

    // ---- prologue: tile0 -> Bt[0]; tile1 -> pfB ----
    const int sf = t >> 1, shalf = t & 1;
    const int4* gsrc = (const int4*)(WxT + (size_t)sf * N_NODES + jc);
    int4 pfA0, pfA1, pfB0, pfB1;
    pfA0 = gsrc[shalf * 2 + 0];           pfA1 = gsrc[shalf * 2 + 1];
    pfB0 = gsrc[4 + shalf * 2 + 0];       pfB1 = gsrc[4 + shalf * 2 + 1];
    {
        int4* ld = (int4*)&Bt[0][sf][shalf * 16];
        ld[0] = pfA0; ld[1] = pfA1;
    }
    __syncthreads();

    // ---- per-lane constants ----
    const int   iL  = mh * 16 + col;             // local row (A-frag row = lane&15)
    const int   i   = i0 + iL;
    const float si  = s_srcT[(size_t)h * N_NODES + i];
    const float gm  = funkey(gmax[h]);
    const float em0 = si + gm;
    const float mi_ = fmaxf(em0, SLOPE * em0);   // lrelu(si + gmax)
    const float Ai  = __expf(si - mi_);
    const float A2i = __expf(0.2f * si - mi_);
    const float Ti  = __expf(-si);

    f32x4 cacc[4], cl;
    #pragma unroll
    for (int n = 0; n < 4; ++n)
        #pragma unroll
        for (int r2 = 0; r2 < 4; ++r2) cacc[n][r2] = 0.f;
    #pragma unroll
    for (int r2 = 0; r2 < 4; ++r2) cl[r2] = 0.f;

    bf16x8 onesf;
    #pragma unroll
    for (int e = 0; e < 8; ++e) onesf[e] = (col == 0) ? (short)0x3F80 : (short)0;

    #pragma unroll 2
    for (int ks = 0; ks < NSTEP; ++ks) {
        const int cur = ks & 1;

        // 1) write tile ks+1 into Bt[cur^1] (source loaded during step ks-1)
        if (ks + 1 < NSTEP) {
            int4* ld = (int4*)&Bt[cur ^ 1][sf][shalf * 16];
            if (cur) { ld[0] = pfA0; ld[1] = pfA1; }
            else     { ld[0] = pfB0; ld[1] = pfB1; }
        }
        // 2) issue loads for tile ks+2
        if (ks + 2 < NSTEP) {
            if (cur) { pfB0 = gsrc[(ks + 2) * 4 + shalf * 2]; pfB1 = gsrc[(ks + 2) * 4 + shalf * 2 + 1]; }
            else     { pfA0 = gsrc[(ks + 2) * 4 + shalf * 2]; pfA1 = gsrc[(ks + 2) * 4 + shalf * 2 + 1]; }
        }

        // 3) A fragment: p for 8 j's (j = ks*32 + q*8 + jj), exp-free
        uint32_t wq = adjW[iL][ks] >> (q * 8);
        float ej[16];
        {
            const float* eb = &EJ[h * 2048 + (ks * 32 + q * 8) * 2];
            *(float4*)&ej[0]  = *(const float4*)&eb[0];
            *(float4*)&ej[4]  = *(const float4*)&eb[4];
            *(float4*)&ej[8]  = *(const float4*)&eb[8];
            *(float4*)&ej[12] = *(const float4*)&eb[12];
        }
        union { uint32_t w[4]; bf16x8 v; } apu;
        #pragma unroll
        for (int pp = 0; pp < 4; ++pp) {
            float B0 = ej[4 * pp + 0], B20 = ej[4 * pp + 1];
            bool pos0 = B0 >= Ti;
            float pv0 = (pos0 ? Ai : A2i) * (pos0 ? B0 : B20);
            pv0 = (wq & (1u << (2 * pp))) ? pv0 : 0.f;
            float B1 = ej[4 * pp + 2], B21 = ej[4 * pp + 3];
            bool pos1 = B1 >= Ti;
            float pv1 = (pos1 ? Ai : A2i) * (pos1 ? B1 : B21);
            pv1 = (wq & (1u << (2 * pp + 1))) ? pv1 : 0.f;
            apu.w[pp] = __builtin_amdgcn_perm(__float_as_uint(pv1), __float_as_uint(pv0),
                                              0x07060302u);
        }

        // 4) MFMA against 4 d-tiles + ones column
        #pragma unroll
        for (int n = 0; n < 4; ++n) {
            bf16x8 bfr = *(const bf16x8*)&Bt[cur][h * 64 + n * 16 + col][q * 8];
            cacc[n] = __builtin_amdgcn_mfma_f32_16x16x32_bf16(apu.v, bfr, cacc[n], 0, 0, 0);
        }
        cl = __builtin_amdgcn_mfma_f32_16x16x32_bf16(apu.v, onesf, cl, 0, 0, 0);

        __syncthreads();
    }

    // ---- epilogue: C layout col=lane&15, row=(lane>>4)*4+reg ----
    #pragma unroll
    for (int n = 0; n < 4; ++n)
        #pragma unroll
        for (int r = 0; r < 4; ++r) {
            int ii = i0 + mh * 16 + q * 4 + r;
            ws_acc[((size_t)chunk * N_NODES + ii) * FEAT + h * 64 + n * 16 + col] = cacc[n][r];
        }
    if (col == 0) {
        #pragma unroll
        for (int r = 0; r < 4; ++r) {
            int ii = i0 + mh * 16 + q * 4 + r;
            ws_l[((size_t)chunk * N_NODES + ii) * H_HEADS + h] = cl[r];
        }
    }
}

// ---------------------------------------------------------------------------
// Finalize: one wave per row, float4 per lane. No LDS, no barriers.
// grid 1024 x 256 (4 rows/block).
// ---------------------------------------------------------------------------
__global__ __launch_bounds__(256) void finalize_kernel(const float* __restrict__ x,
                                                       const float* __restrict__ gamma,
                                                       const float* __restrict__ beta,
                                                       const float* __restrict__ ws_l,
                                                       const float* __restrict__ ws_acc,
                                                       float* __restrict__ out) {
    const int w    = threadIdx.x >> 6;
    const int lane = threadIdx.x & 63;
    const int i    = blockIdx.x * 4 + w;
    const int h    = lane >> 4;

    float L = 0.f;
    float4 y = make_float4(0.f, 0.f, 0.f, 0.f);
    #pragma unroll
    for (int c = 0; c < NCHUNK; ++c) {
        L += ws_l[((size_t)c * N_NODES + i) * H_HEADS + h];
        float4 v = *(const float4*)&ws_acc[((size_t)c * N_NODES + i) * FEAT + lane * 4];
        y.x += v.x; y.y += v.y; y.z += v.z; y.w += v.w;
    }
    float inv = (L > 0.f) ? (1.f / L) : 0.f;
    float4 xv = *(const float4*)&x[(size_t)i * FEAT + lane * 4];
    y.x = y.x * inv + xv.x; y.y = y.y * inv + xv.y;
    y.z = y.z * inv + xv.z; y.w = y.w * inv + xv.w;

    float s1 = y.x + y.y + y.z + y.w;
    float s2 = y.x * y.x + y.y * y.y + y.z * y.z + y.w * y.w;
    #pragma unroll
    for (int o = 32; o > 0; o >>= 1) {
        s1 += __shfl_xor(s1, o, 64);
        s2 += __shfl_xor(s2, o, 64);
    }
    float mu  = s1 * (1.f / 256.f);
    float var = s2 * (1.f / 256.f) - mu * mu;
    float r = 1.0f / sqrtf(var + LN_EPS);
    float4 g = *(const float4*)&gamma[lane * 4];
    float4 b = *(const float4*)&beta[lane * 4];
    float4 o4;
    o4.x = (y.x - mu) * r * g.x + b.x;
    o4.y = (y.y - mu) * r * g.y + b.y;
    o4.z = (y.z - mu) * r * g.z + b.z;
    o4.w = (y.w - mu) * r * g.w + b.w;
    *(float4*)&out[(size_t)i * FEAT + lane * 4] = o4;
}

// ---------------------------------------------------------------------------
extern "C" void kernel_launch(void* const* d_in, const int* in_sizes, int n_in,
                              void* d_out, int out_size, void* d_ws, size_t ws_size,
                              hipStream_t stream) {
    const float* x     = (const float*)d_in[0];
    const void*  adj   = d_in[1];
    const float* W     = (const float*)d_in[2];
    const float* a     = (const float*)d_in[3];
    const float* gamma = (const float*)d_in[4];
    const float* beta  = (const float*)d_in[5];
    float* out = (float*)d_out;

    char* ws = (char*)d_ws;
    uint32_t* gmax    = (uint32_t*)(ws + GMAX_OFF);
    uint32_t* adjbits = (uint32_t*)(ws + ADJB_OFF);
    short*    WxT     = (short*)(ws + WXT_OFF);
    float*    s_srcT  = (float*)(ws + SSRC_OFF);
    float2*   etab    = (float2*)(ws + ETAB_OFF);
    float*    ws_l    = (float*)(ws + WSL_OFF);
    float*    ws_acc  = (float*)(ws + WSACC_OFF);

    pack_adj<<<2048, 256, 0, stream>>>(adj, adjbits, gmax);
    gemm_wx<<<dim3(4, 64), 256, 0, stream>>>(x, W, a, WxT, s_srcT, etab, gmax);
    attn_chunk<<<512, 512, 0, stream>>>(WxT, s_srcT, etab, adjbits, gmax, ws_l, ws_acc);
    finalize_kernel<<<1024, 256, 0, stream>>>(x, gamma, beta, ws_l, ws_acc, out);
}